// Round 22
// baseline (406.297 us; speedup 1.0000x reference)
//
#include <hip/hip_runtime.h>
#include <hip/hip_bf16.h>
#include <cstdint>
#include <cstddef>

#define T_SEQ 4096
#define HID   2048
#define NH    16
#define HD    128
#define QKVN  6144
#define KVB   32
#define CHT   16          // KV tiles per chunk
#define CPH   144         // chunks per head
#define SCL2  0.12753224f /* (1/sqrt(128)) * log2(e) */

typedef unsigned short u16;
typedef unsigned int u32;
typedef __bf16 bf16x8 __attribute__((ext_vector_type(8)));
typedef __bf16 bf16x4 __attribute__((ext_vector_type(4)));
typedef float  f32x4  __attribute__((ext_vector_type(4)));

typedef const __attribute__((address_space(1))) void* gas_ptr;
typedef __attribute__((address_space(3))) void* las_ptr;

__device__ __forceinline__ void async16(const void* g, void* l) {
  __builtin_amdgcn_global_load_lds((gas_ptr)g, (las_ptr)l, 16, 0, 0);
}

__device__ __forceinline__ u16 f2bf(float f) {
  unsigned int u = __float_as_uint(f);
  u += 0x7fffu + ((u >> 16) & 1u);
  return (u16)(u >> 16);
}

__device__ __forceinline__ float bf2f(u16 x) {
  return __uint_as_float((unsigned)x << 16);
}

// ---------------- elementwise cast f32 -> bf16 ----------------
__global__ void cast_f32_bf16(const float* __restrict__ in, u16* __restrict__ out, int n) {
  int i = (blockIdx.x * blockDim.x + threadIdx.x) * 4;
  if (i >= n) return;
  float4 v = *(const float4*)&in[i];
  uint2 o;
  o.x = (unsigned)f2bf(v.x) | ((unsigned)f2bf(v.y) << 16);
  o.y = (unsigned)f2bf(v.z) | ((unsigned)f2bf(v.w) << 16);
  *(uint2*)&out[i] = o;
}

// ---------------- transpose + cast: f32 [R][C] -> bf16 [C][R] ----------------
__global__ void transpose_cast(const float* __restrict__ in, u16* __restrict__ out,
                               int R, int C) {
  __shared__ float tile[64][65];
  int c0 = blockIdx.x * 64, r0 = blockIdx.y * 64;
  int tid = threadIdx.x;
#pragma unroll
  for (int i = 0; i < 16; ++i) {
    int e = i * 256 + tid;
    int rr = e >> 6, cc = e & 63;
    tile[rr][cc] = in[(size_t)(r0 + rr) * C + c0 + cc];
  }
  __syncthreads();
#pragma unroll
  for (int i = 0; i < 16; ++i) {
    int e = i * 256 + tid;
    int oc = e >> 6, orr = e & 63;
    out[(size_t)(c0 + oc) * R + r0 + orr] = f2bf(tile[orr][oc]);
  }
}

// ---------------- cos/sin table for RoPE: cs[t*64+dt] = (cos, sin) ---------------
__global__ void cs_init(const int* __restrict__ pos, float2* __restrict__ cs) {
  int idx = blockIdx.x * 256 + threadIdx.x;     // T_SEQ*64 threads
  int t = idx >> 6, dt = idx & 63;
  float inv = exp2f((float)dt * -0.20762050594046932f);
  float f = (float)pos[t] * inv;
  float s, c;
  __sincosf(f, &s, &c);
  cs[idx] = make_float2(c, s);
}

// ---------------- GEMM: C[M][N] = A[M][K] * BT[N][K]^T  (bf16 in) ----------------
// 128x128 tile, BK=32, plain dbuf; key-swizzled LDS. Wave tile 32x128
// (acc[2][8]) so RoPE pairs (d, d+64) are lane-local.
// MODE 0: plain write (OUT = float). MODE 1: QKV-fused — Q/K col-blocks apply
// RoPE and write head-major Qh/Kh; V blocks transpose in LDS (reusing the
// staging union after the K-loop) and write Vt[h][d][t] coalesced.
template <int MODE, typename OUT>
__global__ __launch_bounds__(256)
void gemm_bf16_bt(const u16* __restrict__ A, const u16* __restrict__ BT,
                  OUT* __restrict__ C, u16* __restrict__ Qh, u16* __restrict__ Kh,
                  u16* __restrict__ Vt, const float2* __restrict__ cs,
                  int M, int N, int K) {
  __shared__ __align__(16) u16 sm[16384];   // As = sm[0..8191], Bs = sm[8192..]
  int tid = threadIdx.x;
  int row0 = blockIdx.y * 128, col0 = blockIdx.x * 128;
  int wv = tid >> 6, lane = tid & 63, lr = lane & 15, lq = lane >> 4;
  int wm = wv * 32;
  f32x4 acc[2][8] = {};

  auto stage = [&](int buf, int ks) {
#pragma unroll
    for (int k = 0; k < 2; ++k) {
      int c = k * 256 + tid;            // 512 chunks/matrix; dest lane-linear
      int row = c >> 2, col = c & 3;
      int key = (row >> 1) & 3;
      async16(&A[(size_t)(row0 + row) * K + ks + (col ^ key) * 8],
              &sm[buf * 4096 + c * 8]);
      async16(&BT[(size_t)(col0 + row) * K + ks + (col ^ key) * 8],
              &sm[8192 + buf * 4096 + c * 8]);
    }
  };

  stage(0, 0);
  __syncthreads();
  int nk = K >> 5;
  for (int t = 0; t < nk; ++t) {
    int cur = t & 1;
    if (t + 1 < nk) stage(cur ^ 1, (t + 1) * 32);

    const char* AsB = (const char*)&sm[cur * 4096];
    const char* BsB = (const char*)&sm[8192 + cur * 4096];
    bf16x8 a[2], b[8];
#pragma unroll
    for (int mi = 0; mi < 2; ++mi) {
      int row = wm + mi * 16 + lr;
      a[mi] = *(const bf16x8*)(AsB + row * 64 + ((lq ^ ((row >> 1) & 3)) << 4));
    }
#pragma unroll
    for (int ni = 0; ni < 8; ++ni) {
      int row = ni * 16 + lr;
      b[ni] = *(const bf16x8*)(BsB + row * 64 + ((lq ^ ((row >> 1) & 3)) << 4));
    }
#pragma unroll
    for (int mi = 0; mi < 2; ++mi)
#pragma unroll
      for (int ni = 0; ni < 8; ++ni)
        acc[mi][ni] = __builtin_amdgcn_mfma_f32_16x16x32_bf16(a[mi], b[ni], acc[mi][ni], 0, 0, 0);
    __syncthreads();
  }

  if constexpr (MODE == 1) {
    int sec = col0 >> 11;                  // 0=Q, 1=K, 2=V
    int hh = (col0 & (HID - 1)) >> 7;      // head within section
    if (sec < 2) {
      u16* dst = (sec == 0) ? Qh : Kh;
      float scl = (sec == 0) ? SCL2 : 1.0f;
#pragma unroll
      for (int mi = 0; mi < 2; ++mi)
#pragma unroll
        for (int r = 0; r < 4; ++r) {
          int t = row0 + wm + mi * 16 + lq * 4 + r;
#pragma unroll
          for (int nj = 0; nj < 4; ++nj) {
            float2 csv = cs[t * 64 + nj * 16 + lr];
            float v1 = acc[mi][nj][r], v2 = acc[mi][nj + 4][r];
            float o1 = (v1 * csv.x - v2 * csv.y) * scl;
            float o2 = (v2 * csv.x + v1 * csv.y) * scl;
            size_t ob = ((size_t)hh * T_SEQ + t) * HD + nj * 16 + lr;
            dst[ob] = f2bf(o1);
            dst[ob + 64] = f2bf(o2);
          }
        }
    } else {
      // V: transpose via LDS (staging union is dead after the K-loop),
      // then write Vt[h][d][t] as coalesced 256B rows.
      // LDS layout [d][t], 256B rows, XOR swizzle byte ^= (d&7)<<4.
      char* smB = (char*)sm;
#pragma unroll
      for (int mi = 0; mi < 2; ++mi)
#pragma unroll
        for (int ni = 0; ni < 8; ++ni) {
          int d = ni * 16 + lr;
          int t4 = wm + mi * 16 + lq * 4;           // t_loc of r=0 (4-aligned)
          bf16x4 pk;
          pk[0] = (__bf16)acc[mi][ni][0];
          pk[1] = (__bf16)acc[mi][ni][1];
          pk[2] = (__bf16)acc[mi][ni][2];
          pk[3] = (__bf16)acc[mi][ni][3];
          *(bf16x4*)(smB + ((d * 256 + t4 * 2) ^ ((d & 7) << 4))) = pk;
        }
      __syncthreads();
#pragma unroll
      for (int j = 0; j < 8; ++j) {
        int d = (tid >> 4) + j * 16;
        int tc = tid & 15;
        bf16x8 v = *(const bf16x8*)(smB + ((d * 256 + tc * 16) ^ ((d & 7) << 4)));
        *(bf16x8*)&Vt[((size_t)hh * HD + d) * T_SEQ + row0 + tc * 8] = v;
      }
    }
  } else {
#pragma unroll
    for (int mi = 0; mi < 2; ++mi)
#pragma unroll
      for (int ni = 0; ni < 8; ++ni)
#pragma unroll
        for (int r = 0; r < 4; ++r)
          C[(size_t)(row0 + wm + mi * 16 + lq * 4 + r) * N + col0 + ni * 16 + lr] =
              (OUT)acc[mi][ni][r];
  }
}

// ---------------- causal flash attention: chunked + transposed pipeline ----------
__global__ __launch_bounds__(256)
void attn_fwd(const u16* __restrict__ Qh, const u16* __restrict__ Kh,
              const u16* __restrict__ Vt, u16* __restrict__ Opart,
              float2* __restrict__ ml, u16* __restrict__ attn) {
  __shared__ u16 Ks[2][32 * 128];   // [kv][d] 256B rows, XOR-8 swizzle
  __shared__ u16 Vs[2][128 * 32];   // [d][kv] 64B rows, key=(row>>1)&3
  __shared__ u16 Ps[4][32 * 32];    // per-wave [q][kv] 64B rows, key=(row>>1)&3

  int tid = threadIdx.x;
  int wv = tid >> 6, lane = tid & 63, lr = lane & 15, lq = lane >> 4;
  char* PsB = (char*)&Ps[wv][0];

  // block -> (h, chunk w). LPT: reverse w so long chunks (large bq) go first.
  int id = blockIdx.x;
  int h = id / CPH;
  int w = (CPH - 1) - (id - h * CPH);
  int slot = h * CPH + w;            // chunk-identity slot for Opart/ml
  int bq = 0, acc = 0;
  for (;;) {
    int ch = (bq + 4) >> 2;
    if (w < acc + ch) break;
    acc += ch;
    ++bq;
  }
  int c = w - acc;
  int nt = 4 * bq + 4;
  int j0 = c * CHT, j1 = min(j0 + CHT, nt);
  int q0 = bq * 128, wrow0 = q0 + wv * 32;

  // Q fragments (pre-scaled): rows wrow0 + qi*16 + lr, k = kd*32 + lq*8
  bf16x8 qf[2][4];
#pragma unroll
  for (int qi = 0; qi < 2; ++qi)
#pragma unroll
    for (int kd = 0; kd < 4; ++kd)
      qf[qi][kd] = *(const bf16x8*)
          &Qh[((size_t)h * T_SEQ + wrow0 + qi * 16 + lr) * HD + kd * 32 + lq * 8];

  f32x4 acc_ot[8][2] = {};          // O^T: acc_ot[di][qi], lane: q=qi*16+lr,
                                    //      d = di*16 + lq*4 + r
  float m_run[2] = {-1e30f, -1e30f};
  float l_run[2] = {0.0f, 0.0f};

  auto stage = [&](int buf, int jb) {
#pragma unroll
    for (int k = 0; k < 2; ++k) {      // K tile: 512 chunks, 16/row, src pre-swz
      int cc = k * 256 + tid;
      int row = cc >> 4;
      int sc = (cc ^ (row & 7)) & 15;
      async16(&Kh[((size_t)h * T_SEQ + jb + row) * HD + sc * 8], &Ks[buf][cc * 8]);
    }
#pragma unroll
    for (int k = 0; k < 2; ++k) {      // V tile: 512 chunks, 4/row, key-swz
      int cc = k * 256 + tid;
      int row = cc >> 2, col = cc & 3;
      int key = (row >> 1) & 3;
      async16(&Vt[((size_t)h * HD + row) * T_SEQ + jb + (col ^ key) * 8],
              &Vs[buf][cc * 8]);
    }
  };

  stage(0, j0 * KVB);
  __syncthreads();

  for (int j = j0; j < j1; ++j) {
    int cur = (j - j0) & 1;
    int jb = j * KVB;
    if (j + 1 < j1) stage(cur ^ 1, jb + KVB);

    if (jb <= wrow0 + 31) {
      const char* KsB = (const char*)&Ks[cur][0];
      const char* VsB = (const char*)&Vs[cur][0];

      // ---- S^T = K Q^T (swapped): st[kj][qi][r] = S[k=jb+kj*16+lq*4+r]
      //      [q=wrow0+qi*16+lr] ----
      f32x4 st[2][2] = {};
#pragma unroll
      for (int kd = 0; kd < 4; ++kd) {
#pragma unroll
        for (int kj = 0; kj < 2; ++kj) {
          int row = kj * 16 + lr;
          int byt = (row << 8) + kd * 64 + lq * 16;
          bf16x8 kf = *(const bf16x8*)(KsB + (byt ^ ((row & 7) << 4)));
#pragma unroll
          for (int qi = 0; qi < 2; ++qi)
            st[kj][qi] = __builtin_amdgcn_mfma_f32_16x16x32_bf16(
                kf, qf[qi][kd], st[kj][qi], 0, 0, 0);
        }
      }

      // ---- causal mask (in-lane) ----
      if (jb + KVB - 1 > wrow0) {
#pragma unroll
        for (int qi = 0; qi < 2; ++qi) {
          int qg = wrow0 + qi * 16 + lr;
#pragma unroll
          for (int kj = 0; kj < 2; ++kj)
#pragma unroll
            for (int r = 0; r < 4; ++r)
              if (jb + kj * 16 + lq * 4 + r > qg) st[kj][qi][r] = -1e30f;
        }
      }

      // ---- in-register softmax per q-column ----
      float sf[2];
#pragma unroll
      for (int qi = 0; qi < 2; ++qi) {
        float mx = fmaxf(fmaxf(fmaxf(st[0][qi][0], st[0][qi][1]),
                               fmaxf(st[0][qi][2], st[0][qi][3])),
                         fmaxf(fmaxf(st[1][qi][0], st[1][qi][1]),
                               fmaxf(st[1][qi][2], st[1][qi][3])));
        mx = fmaxf(mx, __shfl_xor(mx, 16));
        mx = fmaxf(mx, __shfl_xor(mx, 32));
        float mnew = fmaxf(m_run[qi], mx);
        sf[qi] = exp2f(m_run[qi] - mnew);
        m_run[qi] = mnew;

        int rowb = (qi * 16 + lr) * 64;
        int key = ((lr >> 1) & 3) << 4;
        float rs = 0.0f;
#pragma unroll
        for (int kj = 0; kj < 2; ++kj) {
          float p0 = exp2f(st[kj][qi][0] - mnew);
          float p1 = exp2f(st[kj][qi][1] - mnew);
          float p2 = exp2f(st[kj][qi][2] - mnew);
          float p3 = exp2f(st[kj][qi][3] - mnew);
          rs += (p0 + p1) + (p2 + p3);
          bf16x4 pk;
          pk[0] = (__bf16)p0; pk[1] = (__bf16)p1;
          pk[2] = (__bf16)p2; pk[3] = (__bf16)p3;
          *(bf16x4*)(PsB + rowb + (((kj * 16 + lq * 4) * 2) ^ key)) = pk;
        }
        l_run[qi] = l_run[qi] * sf[qi] + rs;   // per-lane partial (lq-slice)
      }

      // ---- rescale O^T (lane-local; skip when no max grew: exact) ----
      if (__any((sf[0] < 1.0f) || (sf[1] < 1.0f))) {
#pragma unroll
        for (int di = 0; di < 8; ++di)
#pragma unroll
          for (int qi = 0; qi < 2; ++qi)
#pragma unroll
            for (int r = 0; r < 4; ++r) acc_ot[di][qi][r] *= sf[qi];
      }

      // ---- O^T += V^T P^T  (128 x 32, K=32): same LDS reads, swapped roles ----
      bf16x8 pa[2];
#pragma unroll
      for (int qi = 0; qi < 2; ++qi) {
        int prow = qi * 16 + lr;
        pa[qi] = *(const bf16x8*)(PsB + prow * 64 + ((lq ^ ((lr >> 1) & 3)) << 4));
      }
#pragma unroll
      for (int di = 0; di < 8; ++di) {
        int vrow = di * 16 + lr;
        bf16x8 vb = *(const bf16x8*)(VsB + vrow * 64 + ((lq ^ ((vrow >> 1) & 3)) << 4));
#pragma unroll
        for (int qi = 0; qi < 2; ++qi)
          acc_ot[di][qi] = __builtin_amdgcn_mfma_f32_16x16x32_bf16(
              vb, pa[qi], acc_ot[di][qi], 0, 0, 0);
      }
    }
    __syncthreads();
  }

  if (bq < 4) {
    // single-chunk bq: normalize in-register, write attn_b directly
#pragma unroll
    for (int qi = 0; qi < 2; ++qi) {
      float l = l_run[qi];
      l += __shfl_xor(l, 16);
      l += __shfl_xor(l, 32);
      float rl = 1.0f / l;
      int qrow = q0 + wv * 32 + qi * 16 + lr;
#pragma unroll
      for (int di = 0; di < 8; ++di) {
        bf16x4 pk;
        pk[0] = (__bf16)(acc_ot[di][qi][0] * rl);
        pk[1] = (__bf16)(acc_ot[di][qi][1] * rl);
        pk[2] = (__bf16)(acc_ot[di][qi][2] * rl);
        pk[3] = (__bf16)(acc_ot[di][qi][3] * rl);
        *(bf16x4*)&attn[(size_t)qrow * HID + h * HD + di * 16 + lq * 4] = pk;
      }
    }
  } else {
    // multi-chunk: unnormalized bf16 O-partial + per-row (m,l) into chunk slot
    u16* Op = Opart + (size_t)slot * 128 * 128;
#pragma unroll
    for (int qi = 0; qi < 2; ++qi) {
      float l = l_run[qi];
      l += __shfl_xor(l, 16);
      l += __shfl_xor(l, 32);
      int q = wv * 32 + qi * 16 + lr;
      if (lq == 0) ml[(size_t)slot * 128 + q] = make_float2(m_run[qi], l);
#pragma unroll
      for (int di = 0; di < 8; ++di) {
        bf16x4 pk;
        pk[0] = (__bf16)acc_ot[di][qi][0];
        pk[1] = (__bf16)acc_ot[di][qi][1];
        pk[2] = (__bf16)acc_ot[di][qi][2];
        pk[3] = (__bf16)acc_ot[di][qi][3];
        *(bf16x4*)&Op[q * 128 + di * 16 + lq * 4] = pk;
      }
    }
  }
}

// ---------------- combine: merge chunk partials -> bf16 attn ---------------------
__global__ __launch_bounds__(256)
void attn_combine(const u16* __restrict__ Opart, const float2* __restrict__ ml,
                  u16* __restrict__ attn) {
  int idx = blockIdx.x * 256 + threadIdx.x;       // T*HID/8 threads
  int e8 = idx * 8;
  int qrow = e8 >> 11;
  int bq = qrow >> 7;
  if (bq < 4) return;                             // written by attn_fwd fast path
  int col = e8 & (HID - 1);
  int h = col >> 7, coll = col & 127;
  int ql = qrow & 127;
  int a = bq >> 2, r = bq & 3;
  int base = h * CPH + (a + 1) * (2 * a + r);
  int n = (bq + 4) >> 2;

  // cache ml pairs in registers (single pass over global)
  float2 mlc[8];
  float m = -1e30f;
  for (int c = 0; c < n; ++c) {
    mlc[c] = ml[(size_t)(base + c) * 128 + ql];
    m = fmaxf(m, mlc[c].x);
  }
  float lsum = 0.0f;
  float o[8] = {};
  for (int c = 0; c < n; ++c) {
    float wgt = exp2f(mlc[c].x - m);
    lsum += mlc[c].y * wgt;
    const u16* src = Opart + ((size_t)(base + c) * 128 + ql) * 128 + coll;
    ushort4 v0 = *(const ushort4*)src;
    ushort4 v1 = *(const ushort4*)(src + 4);
    o[0] += bf2f(v0.x) * wgt; o[1] += bf2f(v0.y) * wgt;
    o[2] += bf2f(v0.z) * wgt; o[3] += bf2f(v0.w) * wgt;
    o[4] += bf2f(v1.x) * wgt; o[5] += bf2f(v1.y) * wgt;
    o[6] += bf2f(v1.z) * wgt; o[7] += bf2f(v1.w) * wgt;
  }
  float rl = 1.0f / lsum;
  uint4 w;
  w.x = (u32)f2bf(o[0] * rl) | ((u32)f2bf(o[1] * rl) << 16);
  w.y = (u32)f2bf(o[2] * rl) | ((u32)f2bf(o[3] * rl) << 16);
  w.z = (u32)f2bf(o[4] * rl) | ((u32)f2bf(o[5] * rl) << 16);
  w.w = (u32)f2bf(o[6] * rl) | ((u32)f2bf(o[7] * rl) << 16);
  *(uint4*)&attn[e8] = w;
}

extern "C" void kernel_launch(void* const* d_in, const int* in_sizes, int n_in,
                              void* d_out, int out_size, void* d_ws, size_t ws_size,
                              hipStream_t stream) {
  const float* hidden    = (const float*)d_in[0];
  const int*   positions = (const int*)d_in[1];
  const float* w_qkv     = (const float*)d_in[2];
  const float* w_o       = (const float*)d_in[3];
  float* out = (float*)d_out;

  char* p = (char*)d_ws;
  u16* woT    = (u16*)p;  p += (size_t)HID * HID * 2;
  u16* Qh     = (u16*)p;  p += (size_t)T_SEQ * HID * 2;
  u16* Kh     = (u16*)p;  p += (size_t)T_SEQ * HID * 2;
  u16* Vt     = (u16*)p;  p += (size_t)T_SEQ * HID * 2;
  u16* attn_b = (u16*)p;  p += (size_t)T_SEQ * HID * 2;
  float2* cs  = (float2*)p; p += (size_t)T_SEQ * 64 * sizeof(float2);
  // union region: {hs_b, wqkvT} (dead after gemm1) overlaps {Opart, ml}
  // (written by attn_fwd, strictly later in stream order).
  char* un = p;
  u16* hs_b   = (u16*)un;
  u16* wqkvT  = (u16*)(un + (size_t)T_SEQ * HID * 2);
  u16* Opart  = (u16*)un;
  float2* ml  = (float2*)(un + (size_t)NH * CPH * 128 * 128 * 2);

  cast_f32_bf16<<<(T_SEQ * HID / 4 + 255) / 256, 256, 0, stream>>>(hidden, hs_b, T_SEQ * HID);
  transpose_cast<<<dim3(QKVN / 64, HID / 64), 256, 0, stream>>>(w_qkv, wqkvT, HID, QKVN);
  transpose_cast<<<dim3(HID / 64, HID / 64), 256, 0, stream>>>(w_o, woT, HID, HID);
  cs_init<<<T_SEQ * 64 / 256, 256, 0, stream>>>(positions, cs);
  gemm_bf16_bt<1, u16><<<dim3(QKVN / 128, T_SEQ / 128), 256, 0, stream>>>(
      hs_b, wqkvT, nullptr, Qh, Kh, Vt, cs, T_SEQ, QKVN, HID);
  attn_fwd<<<NH * CPH, 256, 0, stream>>>(Qh, Kh, Vt, Opart, ml, attn_b);
  attn_combine<<<T_SEQ * HID / 8 / 256, 256, 0, stream>>>(Opart, ml, attn_b);
  gemm_bf16_bt<0, float><<<dim3(HID / 128, T_SEQ / 128), 256, 0, stream>>>(
      attn_b, woT, out, nullptr, nullptr, nullptr, nullptr, T_SEQ, HID, HID);
}

// Round 23
// 386.876 us; speedup vs baseline: 1.0502x; 1.0502x over previous
//
#include <hip/hip_runtime.h>
#include <hip/hip_bf16.h>
#include <cstdint>
#include <cstddef>

#define T_SEQ 4096
#define HID   2048
#define NH    16
#define HD    128
#define QKVN  6144
#define KVB   32
#define CHT   16          // KV tiles per chunk
#define CPH   144         // chunks per head
#define SCL2  0.12753224f /* (1/sqrt(128)) * log2(e) */

typedef unsigned short u16;
typedef unsigned int u32;
typedef __bf16 bf16x8 __attribute__((ext_vector_type(8)));
typedef __bf16 bf16x4 __attribute__((ext_vector_type(4)));
typedef float  f32x4  __attribute__((ext_vector_type(4)));

typedef const __attribute__((address_space(1))) void* gas_ptr;
typedef __attribute__((address_space(3))) void* las_ptr;

__device__ __forceinline__ void async16(const void* g, void* l) {
  __builtin_amdgcn_global_load_lds((gas_ptr)g, (las_ptr)l, 16, 0, 0);
}

__device__ __forceinline__ u16 f2bf(float f) {
  unsigned int u = __float_as_uint(f);
  u += 0x7fffu + ((u >> 16) & 1u);
  return (u16)(u >> 16);
}

__device__ __forceinline__ float bf2f(u16 x) {
  return __uint_as_float((unsigned)x << 16);
}

// ---------------- elementwise cast f32 -> bf16 ----------------
__global__ void cast_f32_bf16(const float* __restrict__ in, u16* __restrict__ out, int n) {
  int i = (blockIdx.x * blockDim.x + threadIdx.x) * 4;
  if (i >= n) return;
  float4 v = *(const float4*)&in[i];
  uint2 o;
  o.x = (unsigned)f2bf(v.x) | ((unsigned)f2bf(v.y) << 16);
  o.y = (unsigned)f2bf(v.z) | ((unsigned)f2bf(v.w) << 16);
  *(uint2*)&out[i] = o;
}

// ---------------- transpose + cast: f32 [R][C] -> bf16 [C][R] ----------------
__global__ void transpose_cast(const float* __restrict__ in, u16* __restrict__ out,
                               int R, int C) {
  __shared__ float tile[64][65];
  int c0 = blockIdx.x * 64, r0 = blockIdx.y * 64;
  int tid = threadIdx.x;
#pragma unroll
  for (int i = 0; i < 16; ++i) {
    int e = i * 256 + tid;
    int rr = e >> 6, cc = e & 63;
    tile[rr][cc] = in[(size_t)(r0 + rr) * C + c0 + cc];
  }
  __syncthreads();
#pragma unroll
  for (int i = 0; i < 16; ++i) {
    int e = i * 256 + tid;
    int oc = e >> 6, orr = e & 63;
    out[(size_t)(c0 + oc) * R + r0 + orr] = f2bf(tile[orr][oc]);
  }
}

// ---------------- cos/sin table for RoPE: cs[t*64+dt] = (cos, sin) ---------------
__global__ void cs_init(const int* __restrict__ pos, float2* __restrict__ cs) {
  int idx = blockIdx.x * 256 + threadIdx.x;     // T_SEQ*64 threads
  int t = idx >> 6, dt = idx & 63;
  float inv = exp2f((float)dt * -0.20762050594046932f);
  float f = (float)pos[t] * inv;
  float s, c;
  __sincosf(f, &s, &c);
  cs[idx] = make_float2(c, s);
}

// ---------------- GEMM: C[M][N] = A[M][K] * BT[N][K]^T  (bf16 in) ----------------
// 128x128 tile, BK=32, plain dbuf; key-swizzled LDS. Wave tile 32x128
// (acc[2][8]) so RoPE pairs (d, d+64) are lane-local.
// MODE 0: plain write (OUT = float). MODE 1: QKV-fused — Q/K col-blocks apply
// RoPE and write head-major Qh/Kh; V blocks transpose in LDS (reusing the
// staging union after the K-loop) and write Vt[h][d][t] coalesced.
template <int MODE, typename OUT>
__global__ __launch_bounds__(256)
void gemm_bf16_bt(const u16* __restrict__ A, const u16* __restrict__ BT,
                  OUT* __restrict__ C, u16* __restrict__ Qh, u16* __restrict__ Kh,
                  u16* __restrict__ Vt, const float2* __restrict__ cs,
                  int M, int N, int K) {
  __shared__ __align__(16) u16 sm[16384];   // As = sm[0..8191], Bs = sm[8192..]
  int tid = threadIdx.x;
  int row0 = blockIdx.y * 128, col0 = blockIdx.x * 128;
  int wv = tid >> 6, lane = tid & 63, lr = lane & 15, lq = lane >> 4;
  int wm = wv * 32;
  f32x4 acc[2][8] = {};

  auto stage = [&](int buf, int ks) {
#pragma unroll
    for (int k = 0; k < 2; ++k) {
      int c = k * 256 + tid;            // 512 chunks/matrix; dest lane-linear
      int row = c >> 2, col = c & 3;
      int key = (row >> 1) & 3;
      async16(&A[(size_t)(row0 + row) * K + ks + (col ^ key) * 8],
              &sm[buf * 4096 + c * 8]);
      async16(&BT[(size_t)(col0 + row) * K + ks + (col ^ key) * 8],
              &sm[8192 + buf * 4096 + c * 8]);
    }
  };

  stage(0, 0);
  __syncthreads();
  int nk = K >> 5;
  for (int t = 0; t < nk; ++t) {
    int cur = t & 1;
    if (t + 1 < nk) stage(cur ^ 1, (t + 1) * 32);

    const char* AsB = (const char*)&sm[cur * 4096];
    const char* BsB = (const char*)&sm[8192 + cur * 4096];
    bf16x8 a[2], b[8];
#pragma unroll
    for (int mi = 0; mi < 2; ++mi) {
      int row = wm + mi * 16 + lr;
      a[mi] = *(const bf16x8*)(AsB + row * 64 + ((lq ^ ((row >> 1) & 3)) << 4));
    }
#pragma unroll
    for (int ni = 0; ni < 8; ++ni) {
      int row = ni * 16 + lr;
      b[ni] = *(const bf16x8*)(BsB + row * 64 + ((lq ^ ((row >> 1) & 3)) << 4));
    }
#pragma unroll
    for (int mi = 0; mi < 2; ++mi)
#pragma unroll
      for (int ni = 0; ni < 8; ++ni)
        acc[mi][ni] = __builtin_amdgcn_mfma_f32_16x16x32_bf16(a[mi], b[ni], acc[mi][ni], 0, 0, 0);
    __syncthreads();
  }

  if constexpr (MODE == 1) {
    int sec = col0 >> 11;                  // 0=Q, 1=K, 2=V
    int hh = (col0 & (HID - 1)) >> 7;      // head within section
    if (sec < 2) {
      u16* dst = (sec == 0) ? Qh : Kh;
      float scl = (sec == 0) ? SCL2 : 1.0f;
#pragma unroll
      for (int mi = 0; mi < 2; ++mi)
#pragma unroll
        for (int r = 0; r < 4; ++r) {
          int t = row0 + wm + mi * 16 + lq * 4 + r;
#pragma unroll
          for (int nj = 0; nj < 4; ++nj) {
            float2 csv = cs[t * 64 + nj * 16 + lr];
            float v1 = acc[mi][nj][r], v2 = acc[mi][nj + 4][r];
            float o1 = (v1 * csv.x - v2 * csv.y) * scl;
            float o2 = (v2 * csv.x + v1 * csv.y) * scl;
            size_t ob = ((size_t)hh * T_SEQ + t) * HD + nj * 16 + lr;
            dst[ob] = f2bf(o1);
            dst[ob + 64] = f2bf(o2);
          }
        }
    } else {
      // V: transpose via LDS (staging union is dead after the K-loop),
      // then write Vt[h][d][t] as coalesced 256B rows.
      // LDS layout [d][t], 256B rows, XOR swizzle byte ^= (d&7)<<4.
      char* smB = (char*)sm;
#pragma unroll
      for (int mi = 0; mi < 2; ++mi)
#pragma unroll
        for (int ni = 0; ni < 8; ++ni) {
          int d = ni * 16 + lr;
          int t4 = wm + mi * 16 + lq * 4;           // t_loc of r=0 (4-aligned)
          bf16x4 pk;
          pk[0] = (__bf16)acc[mi][ni][0];
          pk[1] = (__bf16)acc[mi][ni][1];
          pk[2] = (__bf16)acc[mi][ni][2];
          pk[3] = (__bf16)acc[mi][ni][3];
          *(bf16x4*)(smB + ((d * 256 + t4 * 2) ^ ((d & 7) << 4))) = pk;
        }
      __syncthreads();
#pragma unroll
      for (int j = 0; j < 8; ++j) {
        int d = (tid >> 4) + j * 16;
        int tc = tid & 15;
        bf16x8 v = *(const bf16x8*)(smB + ((d * 256 + tc * 16) ^ ((d & 7) << 4)));
        *(bf16x8*)&Vt[((size_t)hh * HD + d) * T_SEQ + row0 + tc * 8] = v;
      }
    }
  } else {
#pragma unroll
    for (int mi = 0; mi < 2; ++mi)
#pragma unroll
      for (int ni = 0; ni < 8; ++ni)
#pragma unroll
        for (int r = 0; r < 4; ++r)
          C[(size_t)(row0 + wm + mi * 16 + lq * 4 + r) * N + col0 + ni * 16 + lr] =
              (OUT)acc[mi][ni][r];
  }
}

// ---------------- causal flash attention: chunked + transposed pipeline ----------
__global__ __launch_bounds__(256)
void attn_fwd(const u16* __restrict__ Qh, const u16* __restrict__ Kh,
              const u16* __restrict__ Vt, u16* __restrict__ Opart,
              float2* __restrict__ ml, u16* __restrict__ attn) {
  __shared__ u16 Ks[2][32 * 128];   // [kv][d] 256B rows, XOR-8 swizzle
  __shared__ u16 Vs[2][128 * 32];   // [d][kv] 64B rows, key=(row>>1)&3
  __shared__ u16 Ps[4][32 * 32];    // per-wave [q][kv] 64B rows, key=(row>>1)&3

  int tid = threadIdx.x;
  int wv = tid >> 6, lane = tid & 63, lr = lane & 15, lq = lane >> 4;
  char* PsB = (char*)&Ps[wv][0];

  // block -> (h, chunk w). LPT: reverse w so long chunks (large bq) go first.
  int id = blockIdx.x;
  int h = id / CPH;
  int w = (CPH - 1) - (id - h * CPH);
  int slot = h * CPH + w;            // chunk-identity slot for Opart/ml
  int bq = 0, acc = 0;
  for (;;) {
    int ch = (bq + 4) >> 2;
    if (w < acc + ch) break;
    acc += ch;
    ++bq;
  }
  int c = w - acc;
  int nt = 4 * bq + 4;
  int j0 = c * CHT, j1 = min(j0 + CHT, nt);
  int q0 = bq * 128, wrow0 = q0 + wv * 32;

  // Q fragments (pre-scaled): rows wrow0 + qi*16 + lr, k = kd*32 + lq*8
  bf16x8 qf[2][4];
#pragma unroll
  for (int qi = 0; qi < 2; ++qi)
#pragma unroll
    for (int kd = 0; kd < 4; ++kd)
      qf[qi][kd] = *(const bf16x8*)
          &Qh[((size_t)h * T_SEQ + wrow0 + qi * 16 + lr) * HD + kd * 32 + lq * 8];

  f32x4 acc_ot[8][2] = {};          // O^T: acc_ot[di][qi], lane: q=qi*16+lr,
                                    //      d = di*16 + lq*4 + r
  float m_run[2] = {-1e30f, -1e30f};
  float l_run[2] = {0.0f, 0.0f};

  auto stage = [&](int buf, int jb) {
#pragma unroll
    for (int k = 0; k < 2; ++k) {      // K tile: 512 chunks, 16/row, src pre-swz
      int cc = k * 256 + tid;
      int row = cc >> 4;
      int sc = (cc ^ (row & 7)) & 15;
      async16(&Kh[((size_t)h * T_SEQ + jb + row) * HD + sc * 8], &Ks[buf][cc * 8]);
    }
#pragma unroll
    for (int k = 0; k < 2; ++k) {      // V tile: 512 chunks, 4/row, key-swz
      int cc = k * 256 + tid;
      int row = cc >> 2, col = cc & 3;
      int key = (row >> 1) & 3;
      async16(&Vt[((size_t)h * HD + row) * T_SEQ + jb + (col ^ key) * 8],
              &Vs[buf][cc * 8]);
    }
  };

  stage(0, j0 * KVB);
  __syncthreads();

  for (int j = j0; j < j1; ++j) {
    int cur = (j - j0) & 1;
    int jb = j * KVB;
    if (j + 1 < j1) stage(cur ^ 1, jb + KVB);

    if (jb <= wrow0 + 31) {
      const char* KsB = (const char*)&Ks[cur][0];
      const char* VsB = (const char*)&Vs[cur][0];

      // ---- S^T = K Q^T (swapped): st[kj][qi][r] = S[k=jb+kj*16+lq*4+r]
      //      [q=wrow0+qi*16+lr] ----
      f32x4 st[2][2] = {};
#pragma unroll
      for (int kd = 0; kd < 4; ++kd) {
#pragma unroll
        for (int kj = 0; kj < 2; ++kj) {
          int row = kj * 16 + lr;
          int byt = (row << 8) + kd * 64 + lq * 16;
          bf16x8 kf = *(const bf16x8*)(KsB + (byt ^ ((row & 7) << 4)));
#pragma unroll
          for (int qi = 0; qi < 2; ++qi)
            st[kj][qi] = __builtin_amdgcn_mfma_f32_16x16x32_bf16(
                kf, qf[qi][kd], st[kj][qi], 0, 0, 0);
        }
      }

      // ---- causal mask (in-lane) ----
      if (jb + KVB - 1 > wrow0) {
#pragma unroll
        for (int qi = 0; qi < 2; ++qi) {
          int qg = wrow0 + qi * 16 + lr;
#pragma unroll
          for (int kj = 0; kj < 2; ++kj)
#pragma unroll
            for (int r = 0; r < 4; ++r)
              if (jb + kj * 16 + lq * 4 + r > qg) st[kj][qi][r] = -1e30f;
        }
      }

      // ---- in-register softmax per q-column ----
      float sf[2];
#pragma unroll
      for (int qi = 0; qi < 2; ++qi) {
        float mx = fmaxf(fmaxf(fmaxf(st[0][qi][0], st[0][qi][1]),
                               fmaxf(st[0][qi][2], st[0][qi][3])),
                         fmaxf(fmaxf(st[1][qi][0], st[1][qi][1]),
                               fmaxf(st[1][qi][2], st[1][qi][3])));
        mx = fmaxf(mx, __shfl_xor(mx, 16));
        mx = fmaxf(mx, __shfl_xor(mx, 32));
        float mnew = fmaxf(m_run[qi], mx);
        sf[qi] = exp2f(m_run[qi] - mnew);
        m_run[qi] = mnew;

        int rowb = (qi * 16 + lr) * 64;
        int key = ((lr >> 1) & 3) << 4;
        float rs = 0.0f;
#pragma unroll
        for (int kj = 0; kj < 2; ++kj) {
          float p0 = exp2f(st[kj][qi][0] - mnew);
          float p1 = exp2f(st[kj][qi][1] - mnew);
          float p2 = exp2f(st[kj][qi][2] - mnew);
          float p3 = exp2f(st[kj][qi][3] - mnew);
          rs += (p0 + p1) + (p2 + p3);
          bf16x4 pk;
          pk[0] = (__bf16)p0; pk[1] = (__bf16)p1;
          pk[2] = (__bf16)p2; pk[3] = (__bf16)p3;
          *(bf16x4*)(PsB + rowb + (((kj * 16 + lq * 4) * 2) ^ key)) = pk;
        }
        l_run[qi] = l_run[qi] * sf[qi] + rs;   // per-lane partial (lq-slice)
      }

      // ---- rescale O^T (lane-local; skip when no max grew: exact) ----
      if (__any((sf[0] < 1.0f) || (sf[1] < 1.0f))) {
#pragma unroll
        for (int di = 0; di < 8; ++di)
#pragma unroll
          for (int qi = 0; qi < 2; ++qi)
#pragma unroll
            for (int r = 0; r < 4; ++r) acc_ot[di][qi][r] *= sf[qi];
      }

      // ---- O^T += V^T P^T  (128 x 32, K=32): same LDS reads, swapped roles ----
      bf16x8 pa[2];
#pragma unroll
      for (int qi = 0; qi < 2; ++qi) {
        int prow = qi * 16 + lr;
        pa[qi] = *(const bf16x8*)(PsB + prow * 64 + ((lq ^ ((lr >> 1) & 3)) << 4));
      }
#pragma unroll
      for (int di = 0; di < 8; ++di) {
        int vrow = di * 16 + lr;
        bf16x8 vb = *(const bf16x8*)(VsB + vrow * 64 + ((lq ^ ((vrow >> 1) & 3)) << 4));
#pragma unroll
        for (int qi = 0; qi < 2; ++qi)
          acc_ot[di][qi] = __builtin_amdgcn_mfma_f32_16x16x32_bf16(
              vb, pa[qi], acc_ot[di][qi], 0, 0, 0);
      }
    }
    __syncthreads();
  }

  if (bq < 4) {
    // single-chunk bq: normalize in-register, write attn_b directly
#pragma unroll
    for (int qi = 0; qi < 2; ++qi) {
      float l = l_run[qi];
      l += __shfl_xor(l, 16);
      l += __shfl_xor(l, 32);
      float rl = 1.0f / l;
      int qrow = q0 + wv * 32 + qi * 16 + lr;
#pragma unroll
      for (int di = 0; di < 8; ++di) {
        bf16x4 pk;
        pk[0] = (__bf16)(acc_ot[di][qi][0] * rl);
        pk[1] = (__bf16)(acc_ot[di][qi][1] * rl);
        pk[2] = (__bf16)(acc_ot[di][qi][2] * rl);
        pk[3] = (__bf16)(acc_ot[di][qi][3] * rl);
        *(bf16x4*)&attn[(size_t)qrow * HID + h * HD + di * 16 + lq * 4] = pk;
      }
    }
  } else {
    // multi-chunk: unnormalized bf16 O-partial + per-row (m,l) into chunk slot
    u16* Op = Opart + (size_t)slot * 128 * 128;
#pragma unroll
    for (int qi = 0; qi < 2; ++qi) {
      float l = l_run[qi];
      l += __shfl_xor(l, 16);
      l += __shfl_xor(l, 32);
      int q = wv * 32 + qi * 16 + lr;
      if (lq == 0) ml[(size_t)slot * 128 + q] = make_float2(m_run[qi], l);
#pragma unroll
      for (int di = 0; di < 8; ++di) {
        bf16x4 pk;
        pk[0] = (__bf16)acc_ot[di][qi][0];
        pk[1] = (__bf16)acc_ot[di][qi][1];
        pk[2] = (__bf16)acc_ot[di][qi][2];
        pk[3] = (__bf16)acc_ot[di][qi][3];
        *(bf16x4*)&Op[q * 128 + di * 16 + lq * 4] = pk;
      }
    }
  }
}

// ---------------- combine: merge chunk partials -> bf16 attn ---------------------
__global__ __launch_bounds__(256)
void attn_combine(const u16* __restrict__ Opart, const float2* __restrict__ ml,
                  u16* __restrict__ attn) {
  int idx = blockIdx.x * 256 + threadIdx.x;       // T*HID/8 threads
  int e8 = idx * 8;
  int qrow = e8 >> 11;
  int bq = qrow >> 7;
  if (bq < 4) return;                             // written by attn_fwd fast path
  int col = e8 & (HID - 1);
  int h = col >> 7, coll = col & 127;
  int ql = qrow & 127;
  int a = bq >> 2, r = bq & 3;
  int base = h * CPH + (a + 1) * (2 * a + r);
  int n = (bq + 4) >> 2;

  float m = -1e30f;
  for (int c = 0; c < n; ++c) m = fmaxf(m, ml[(size_t)(base + c) * 128 + ql].x);
  float lsum = 0.0f;
  float o[8] = {};
  for (int c = 0; c < n; ++c) {
    float2 mlc = ml[(size_t)(base + c) * 128 + ql];
    float wgt = exp2f(mlc.x - m);
    lsum += mlc.y * wgt;
    const u16* src = Opart + ((size_t)(base + c) * 128 + ql) * 128 + coll;
    ushort4 v0 = *(const ushort4*)src;
    ushort4 v1 = *(const ushort4*)(src + 4);
    o[0] += bf2f(v0.x) * wgt; o[1] += bf2f(v0.y) * wgt;
    o[2] += bf2f(v0.z) * wgt; o[3] += bf2f(v0.w) * wgt;
    o[4] += bf2f(v1.x) * wgt; o[5] += bf2f(v1.y) * wgt;
    o[6] += bf2f(v1.z) * wgt; o[7] += bf2f(v1.w) * wgt;
  }
  float rl = 1.0f / lsum;
  uint4 w;
  w.x = (u32)f2bf(o[0] * rl) | ((u32)f2bf(o[1] * rl) << 16);
  w.y = (u32)f2bf(o[2] * rl) | ((u32)f2bf(o[3] * rl) << 16);
  w.z = (u32)f2bf(o[4] * rl) | ((u32)f2bf(o[5] * rl) << 16);
  w.w = (u32)f2bf(o[6] * rl) | ((u32)f2bf(o[7] * rl) << 16);
  *(uint4*)&attn[e8] = w;
}

extern "C" void kernel_launch(void* const* d_in, const int* in_sizes, int n_in,
                              void* d_out, int out_size, void* d_ws, size_t ws_size,
                              hipStream_t stream) {
  const float* hidden    = (const float*)d_in[0];
  const int*   positions = (const int*)d_in[1];
  const float* w_qkv     = (const float*)d_in[2];
  const float* w_o       = (const float*)d_in[3];
  float* out = (float*)d_out;

  char* p = (char*)d_ws;
  u16* woT    = (u16*)p;  p += (size_t)HID * HID * 2;
  u16* Qh     = (u16*)p;  p += (size_t)T_SEQ * HID * 2;
  u16* Kh     = (u16*)p;  p += (size_t)T_SEQ * HID * 2;
  u16* Vt     = (u16*)p;  p += (size_t)T_SEQ * HID * 2;
  u16* attn_b = (u16*)p;  p += (size_t)T_SEQ * HID * 2;
  float2* cs  = (float2*)p; p += (size_t)T_SEQ * 64 * sizeof(float2);
  // union region: {hs_b, wqkvT} (dead after gemm1) overlaps {Opart, ml}
  // (written by attn_fwd, strictly later in stream order).
  char* un = p;
  u16* hs_b   = (u16*)un;
  u16* wqkvT  = (u16*)(un + (size_t)T_SEQ * HID * 2);
  u16* Opart  = (u16*)un;
  float2* ml  = (float2*)(un + (size_t)NH * CPH * 128 * 128 * 2);

  cast_f32_bf16<<<(T_SEQ * HID / 4 + 255) / 256, 256, 0, stream>>>(hidden, hs_b, T_SEQ * HID);
  transpose_cast<<<dim3(QKVN / 64, HID / 64), 256, 0, stream>>>(w_qkv, wqkvT, HID, QKVN);
  transpose_cast<<<dim3(HID / 64, HID / 64), 256, 0, stream>>>(w_o, woT, HID, HID);
  cs_init<<<T_SEQ * 64 / 256, 256, 0, stream>>>(positions, cs);
  gemm_bf16_bt<1, u16><<<dim3(QKVN / 128, T_SEQ / 128), 256, 0, stream>>>(
      hs_b, wqkvT, nullptr, Qh, Kh, Vt, cs, T_SEQ, QKVN, HID);
  attn_fwd<<<NH * CPH, 256, 0, stream>>>(Qh, Kh, Vt, Opart, ml, attn_b);
  attn_combine<<<T_SEQ * HID / 8 / 256, 256, 0, stream>>>(Opart, ml, attn_b);
  gemm_bf16_bt<0, float><<<dim3(HID / 128, T_SEQ / 128), 256, 0, stream>>>(
      attn_b, woT, out, nullptr, nullptr, nullptr, nullptr, T_SEQ, HID, HID);
}